// Round 1
// baseline (305.358 us; speedup 1.0000x reference)
//
#include <hip/hip_runtime.h>

#define DIM 128

// One output row = 128 floats = 32 float4. A group of 32 consecutive lanes
// handles one row: each lane computes the bin index (cheap, redundant across
// the group; the distance load is same-address -> HW broadcast) and stores
// one float4 of the gathered embedding row.
__global__ __launch_bounds__(256) void DistanceEmbedding_kernel(
    const float* __restrict__ dist,   // [R] distances, R = B*N*N
    const float* __restrict__ emb,    // [DIM*DIM] embedding table
    const float* __restrict__ bins,   // [DIM] bin centers (monotone increasing)
    float4* __restrict__ out,         // [R*32] output rows, float4-granular
    long long total4)                 // R*32
{
    __shared__ float s_bins[DIM];
    if (threadIdx.x < DIM) s_bins[threadIdx.x] = bins[threadIdx.x];
    __syncthreads();

    // bins = linspace(0, 32, 128) -> spacing 32/127. Closed-form nearest bin
    // is round(d * 127/32); true argmin is within +/-1 of that, so refine
    // against the real bins with first-min tie-break (matches jnp.argmin).
    const float inv_step = 127.0f / 32.0f;

    const long long stride = (long long)gridDim.x * blockDim.x;
    for (long long t = (long long)blockIdx.x * blockDim.x + threadIdx.x;
         t < total4; t += stride) {
        const long long row = t >> 5;       // which distance element
        const int c4 = (int)(t & 31);       // which float4 of the 128-wide row

        const float d = dist[row];
        const float x = d * inv_step;
        int i0 = (int)floorf(x + 0.5f);
        i0 = min(max(i0, 0), DIM - 1);
        const int lo = max(i0 - 1, 0);
        const int hi = min(i0 + 1, DIM - 1);

        int best = lo;
        float bd = fabsf(d - s_bins[lo]);
        #pragma unroll
        for (int i = 0; i < 2; ++i) {
            const int cand = lo + 1 + i;
            if (cand <= hi) {
                const float cd = fabsf(d - s_bins[cand]);
                if (cd < bd) { bd = cd; best = cand; }  // strict <: first-min tie-break
            }
        }

        const float4* erow = (const float4*)(emb + (long long)best * DIM);
        out[t] = erow[c4];
    }
}

extern "C" void kernel_launch(void* const* d_in, const int* in_sizes, int n_in,
                              void* d_out, int out_size, void* d_ws, size_t ws_size,
                              hipStream_t stream) {
    const float* dist = (const float*)d_in[0];   // [2,1024,1024] f32
    const float* emb  = (const float*)d_in[1];   // [128,128] f32
    const float* bins = (const float*)d_in[2];   // [128] f32
    float4* out = (float4*)d_out;                // [2,1024,1024,128] f32

    const long long R = (long long)in_sizes[0];  // number of distance elements
    const long long total4 = R * (DIM / 4);      // float4 units in output

    const int block = 256;
    const int grid = 2048;                        // grid-stride, ~8 blocks/CU
    DistanceEmbedding_kernel<<<grid, block, 0, stream>>>(
        dist, emb, bins, out, total4);
}

// Round 2
// 241.165 us; speedup vs baseline: 1.2662x; 1.2662x over previous
//
#include <hip/hip_runtime.h>

#define DIM 128
#define UNROLL 4

// One output row = 128 floats = 32 float4. A group of 32 consecutive lanes
// handles one row: each lane computes the bin index (cheap, redundant across
// the group; the distance load is same-address -> HW broadcast) and stores
// one float4 of the gathered embedding row.
//
// emb_table (64 KB) is staged in LDS so the store data comes from ds_read
// (lgkm path) instead of a vmem gather -- keeps the vmcnt queue free for
// outstanding stores. block=1024 so 2 blocks/CU (128 KB LDS) still gives
// 8 waves/SIMD.
__global__ __launch_bounds__(1024) void DistanceEmbedding_kernel(
    const float* __restrict__ dist,   // [R] distances, R = B*N*N
    const float4* __restrict__ emb4,  // [DIM*DIM/4] embedding table as float4
    const float* __restrict__ bins,   // [DIM] bin centers (monotone increasing)
    float4* __restrict__ out,         // [R*32] output rows, float4-granular
    long long total4)                 // R*32
{
    __shared__ float s_bins[DIM];
    __shared__ float4 s_emb[DIM * DIM / 4];   // 64 KB

    // Stage embedding table: 4096 float4 / 1024 threads = 4 each.
    #pragma unroll
    for (int i = 0; i < 4; ++i)
        s_emb[threadIdx.x + i * 1024] = emb4[threadIdx.x + i * 1024];
    if (threadIdx.x < DIM) s_bins[threadIdx.x] = bins[threadIdx.x];
    __syncthreads();

    // bins = linspace(0, 32, 128) -> spacing 32/127. Closed-form nearest bin
    // is round(d * 127/32); true argmin is within +/-1, refine against the
    // real bins with first-min tie-break (matches jnp.argmin).
    const float inv_step = 127.0f / 32.0f;

    const long long nthreads = (long long)gridDim.x * blockDim.x;
    const long long base0 = (long long)blockIdx.x * blockDim.x + threadIdx.x;
    const long long big_stride = nthreads * UNROLL;

    long long t0 = base0;
    for (; t0 + (UNROLL - 1) * nthreads < total4; t0 += big_stride) {
        float d[UNROLL];
        #pragma unroll
        for (int k = 0; k < UNROLL; ++k) {
            const long long t = t0 + k * nthreads;
            d[k] = dist[t >> 5];
        }

        float4 v[UNROLL];
        #pragma unroll
        for (int k = 0; k < UNROLL; ++k) {
            const long long t = t0 + k * nthreads;
            const int c4 = (int)(t & 31);

            const float x = d[k] * inv_step;
            int i0 = (int)floorf(x + 0.5f);
            i0 = min(max(i0, 0), DIM - 1);
            const int lo = max(i0 - 1, 0);
            const int hi = min(i0 + 1, DIM - 1);

            int best = lo;
            float bd = fabsf(d[k] - s_bins[lo]);
            #pragma unroll
            for (int i = 0; i < 2; ++i) {
                const int cand = lo + 1 + i;
                if (cand <= hi) {
                    const float cd = fabsf(d[k] - s_bins[cand]);
                    if (cd < bd) { bd = cd; best = cand; }  // strict <: first-min
                }
            }
            v[k] = s_emb[best * (DIM / 4) + c4];
        }

        #pragma unroll
        for (int k = 0; k < UNROLL; ++k)
            out[t0 + k * nthreads] = v[k];
    }

    // Tail (never taken for the bench shape, kept for generality).
    for (; t0 < total4; t0 += nthreads) {
        const float d = dist[t0 >> 5];
        const int c4 = (int)(t0 & 31);
        const float x = d * inv_step;
        int i0 = (int)floorf(x + 0.5f);
        i0 = min(max(i0, 0), DIM - 1);
        const int lo = max(i0 - 1, 0);
        const int hi = min(i0 + 1, DIM - 1);
        int best = lo;
        float bd = fabsf(d - s_bins[lo]);
        for (int cand = lo + 1; cand <= hi; ++cand) {
            const float cd = fabsf(d - s_bins[cand]);
            if (cd < bd) { bd = cd; best = cand; }
        }
        out[t0] = s_emb[best * (DIM / 4) + c4];
    }
}

extern "C" void kernel_launch(void* const* d_in, const int* in_sizes, int n_in,
                              void* d_out, int out_size, void* d_ws, size_t ws_size,
                              hipStream_t stream) {
    const float* dist = (const float*)d_in[0];    // [2,1024,1024] f32
    const float4* emb = (const float4*)d_in[1];   // [128,128] f32
    const float* bins = (const float*)d_in[2];    // [128] f32
    float4* out = (float4*)d_out;                 // [2,1024,1024,128] f32

    const long long R = (long long)in_sizes[0];   // number of distance elements
    const long long total4 = R * (DIM / 4);       // float4 units in output

    const int block = 1024;                       // 2 blocks/CU -> 8 waves/SIMD
    const int grid = 512;
    DistanceEmbedding_kernel<<<grid, block, 0, stream>>>(
        dist, emb, bins, out, total4);
}